// Round 4
// baseline (284.014 us; speedup 1.0000x reference)
//
#include <hip/hip_runtime.h>
#include <hip/hip_bf16.h>

#define F_DIM 128
#define POOL_SEG 16

typedef __attribute__((ext_vector_type(8))) short short8v;   // 8 bf16
typedef __attribute__((ext_vector_type(4))) float float4v;   // MFMA acc

// ---------------- helpers ----------------

__device__ __forceinline__ ushort f2bf(float f) {  // RNE f32 -> bf16
    uint u = __float_as_uint(f);
    u += 0x7fffu + ((u >> 16) & 1u);
    return (ushort)(u >> 16);
}
__device__ __forceinline__ float bf2f(ushort h) {
    return __uint_as_float(((uint)h) << 16);
}
__device__ __forceinline__ void bf2x(uint u, float& a, float& b) {
    a = __uint_as_float((u & 0x0000ffffu) << 16);
    b = __uint_as_float(u & 0xffff0000u);
}

// ---------------- CSR build ----------------

__global__ void count_kernel(const int* __restrict__ dst, int* __restrict__ deg, int E_) {
    int i = blockIdx.x * blockDim.x + threadIdx.x;
    if (i < E_) atomicAdd(&deg[dst[i]], 1);
}

// single-block fused scan: row_ptr (exclusive), rfill copy, dinv, row_ptr[N]=E
#define SCAN_CHUNK 10240
__global__ __launch_bounds__(1024) void scan_all_kernel(
    const int* __restrict__ deg, int* __restrict__ row_ptr, int* __restrict__ rfill,
    float* __restrict__ dinv, int N_, int E_)
{
    __shared__ int chunk[SCAN_CHUNK];
    __shared__ int tsum[1024];
    __shared__ int carry;
    const int t = threadIdx.x;
    if (t == 0) carry = 0;
    __syncthreads();
    for (int base = 0; base < N_; base += SCAN_CHUNK) {
        // coalesced load
        for (int i = t; i < SCAN_CHUNK; i += 1024) {
            int g = base + i;
            chunk[i] = (g < N_) ? deg[g] : 0;
        }
        __syncthreads();
        // serial exclusive scan of my 10 elements
        int off = t * (SCAN_CHUNK / 1024);
        int vals[SCAN_CHUNK / 1024];
        int s = 0;
        #pragma unroll
        for (int j = 0; j < SCAN_CHUNK / 1024; ++j) { vals[j] = s; s += chunk[off + j]; }
        tsum[t] = s;
        __syncthreads();
        // Hillis-Steele inclusive scan over tsum
        for (int d = 1; d < 1024; d <<= 1) {
            int v = (t >= d) ? tsum[t - d] : 0;
            __syncthreads();
            tsum[t] += v;
            __syncthreads();
        }
        int texcl = tsum[t] - s + carry;
        #pragma unroll
        for (int j = 0; j < SCAN_CHUNK / 1024; ++j) {
            int g = base + off + j;
            if (g < N_) {
                int e = texcl + vals[j];
                row_ptr[g] = e;
                rfill[g] = e;
                dinv[g] = 1.0f / sqrtf((float)(chunk[off + j] + 1));
            }
        }
        __syncthreads();
        if (t == 0) carry += tsum[1023];
        __syncthreads();
    }
    if (t == 0) row_ptr[N_] = E_;
}

__global__ void fill_kernel(const int* __restrict__ src, const int* __restrict__ dst,
                            int* __restrict__ cur, int* __restrict__ col_src, int E_) {
    int i = blockIdx.x * blockDim.x + threadIdx.x;
    if (i < E_) {
        int p = atomicAdd(&cur[dst[i]], 1);
        col_src[p] = src[i];
    }
}

// ---------------- W^T prep: Wt[hi/lo][layer][c][k] = split(W[k][c]) ----------------
// grid = 48 blocks (3 layers x 16 col-chunks), 256 threads.

__global__ __launch_bounds__(256) void wprep_kernel(
    const float* __restrict__ W0, const float* __restrict__ W1, const float* __restrict__ W2,
    ushort* __restrict__ Wth, ushort* __restrict__ Wtl)
{
    int layer = blockIdx.x >> 4;
    int chunkc = blockIdx.x & 15;
    const float* W = (layer == 0) ? W0 : (layer == 1) ? W1 : W2;
    int t = threadIdx.x;
    int c  = chunkc * 8 + (t >> 5);      // column of W
    int k0 = (t & 31) * 4;               // 4 consecutive k
    ushort4 hi, lo;
    float v0 = W[(size_t)(k0 + 0) * F_DIM + c];
    float v1 = W[(size_t)(k0 + 1) * F_DIM + c];
    float v2 = W[(size_t)(k0 + 2) * F_DIM + c];
    float v3 = W[(size_t)(k0 + 3) * F_DIM + c];
    hi.x = f2bf(v0); lo.x = f2bf(v0 - bf2f(hi.x));
    hi.y = f2bf(v1); lo.y = f2bf(v1 - bf2f(hi.y));
    hi.z = f2bf(v2); lo.z = f2bf(v2 - bf2f(hi.z));
    hi.w = f2bf(v3); lo.w = f2bf(v3 - bf2f(hi.w));
    size_t o = (size_t)layer * F_DIM * F_DIM + (size_t)c * F_DIM + k0;
    *reinterpret_cast<ushort4*>(&Wth[o]) = hi;
    *reinterpret_cast<ushort4*>(&Wtl[o]) = lo;
}

// ---------------- MFMA GEMM: Mbf[r][c] = bf16( dinv[r] * sum_k in[r][k] * W[k][c] ) ----------------
// bf16 hi/lo split, 3-term (AhBh + AlBh + AhBl) -> ~f32 accuracy.
// 64x64 tile, K=128 fully in LDS, 4 waves (one 16-row strip each), 16x16x32 MFMA.

__global__ __launch_bounds__(256) void gemm_scale_kernel(
    const float* __restrict__ in, const ushort* __restrict__ Wth, const ushort* __restrict__ Wtl,
    const float* __restrict__ dinv, ushort* __restrict__ outbf, int N_)
{
    __shared__ ushort Ah[64 * F_DIM];   // 16 KB each, XOR-swizzled k within row
    __shared__ ushort Al[64 * F_DIM];
    __shared__ ushort Bh[64 * F_DIM];   // [c][k], c = col within tile
    __shared__ ushort Bl[64 * F_DIM];

    const int tid = threadIdx.x;
    const int brow = (blockIdx.x >> 1) * 64;
    const int bcol = (blockIdx.x & 1) * 64;

    // stage A: 64 rows x 16 k-chunks(8 f32) = 1024 chunks, 4 per thread
    #pragma unroll
    for (int i = 0; i < 4; ++i) {
        int chunk = tid + i * 256;
        int r  = chunk >> 4;
        int k0 = (chunk & 15) * 8;
        int row = brow + r;
        float f[8];
        if (row < N_) {
            float4 g0 = *reinterpret_cast<const float4*>(&in[(size_t)row * F_DIM + k0]);
            float4 g1 = *reinterpret_cast<const float4*>(&in[(size_t)row * F_DIM + k0 + 4]);
            f[0] = g0.x; f[1] = g0.y; f[2] = g0.z; f[3] = g0.w;
            f[4] = g1.x; f[5] = g1.y; f[6] = g1.z; f[7] = g1.w;
        } else {
            #pragma unroll
            for (int j = 0; j < 8; ++j) f[j] = 0.f;
        }
        ushort hi[8], lo[8];
        #pragma unroll
        for (int j = 0; j < 8; ++j) {
            hi[j] = f2bf(f[j]);
            lo[j] = f2bf(f[j] - bf2f(hi[j]));
        }
        int idx = r * F_DIM + (k0 ^ ((r & 7) << 3));
        *reinterpret_cast<short8v*>(&Ah[idx]) = *reinterpret_cast<short8v*>(hi);
        *reinterpret_cast<short8v*>(&Al[idx]) = *reinterpret_cast<short8v*>(lo);
    }
    // stage B: Wt rows bcol..bcol+63, same chunking (hi then lo)
    #pragma unroll
    for (int i = 0; i < 4; ++i) {
        int chunk = tid + i * 256;
        int c  = chunk >> 4;
        int k0 = (chunk & 15) * 8;
        size_t go = (size_t)(bcol + c) * F_DIM + k0;
        int idx = c * F_DIM + (k0 ^ ((c & 7) << 3));
        *reinterpret_cast<short8v*>(&Bh[idx]) = *reinterpret_cast<const short8v*>(&Wth[go]);
        *reinterpret_cast<short8v*>(&Bl[idx]) = *reinterpret_cast<const short8v*>(&Wtl[go]);
    }
    __syncthreads();

    const int l = tid & 63;
    const int wave = tid >> 6;
    const int m0 = wave * 16;
    const int row_a = m0 + (l & 15);
    const int kgrp = (l >> 4) * 8;
    const int aswz = (row_a & 7) << 3;

    float4v acc[4] = {{0.f,0.f,0.f,0.f},{0.f,0.f,0.f,0.f},{0.f,0.f,0.f,0.f},{0.f,0.f,0.f,0.f}};

    #pragma unroll
    for (int kk = 0; kk < 4; ++kk) {
        int kbase = kk * 32 + kgrp;
        short8v a_h = *reinterpret_cast<short8v*>(&Ah[row_a * F_DIM + (kbase ^ aswz)]);
        short8v a_l = *reinterpret_cast<short8v*>(&Al[row_a * F_DIM + (kbase ^ aswz)]);
        #pragma unroll
        for (int n = 0; n < 4; ++n) {
            int col_b = n * 16 + (l & 15);
            int bidx = col_b * F_DIM + (kbase ^ ((col_b & 7) << 3));
            short8v b_h = *reinterpret_cast<short8v*>(&Bh[bidx]);
            short8v b_l = *reinterpret_cast<short8v*>(&Bl[bidx]);
            acc[n] = __builtin_amdgcn_mfma_f32_16x16x32_bf16(a_h, b_h, acc[n], 0, 0, 0);
            acc[n] = __builtin_amdgcn_mfma_f32_16x16x32_bf16(a_l, b_h, acc[n], 0, 0, 0);
            acc[n] = __builtin_amdgcn_mfma_f32_16x16x32_bf16(a_h, b_l, acc[n], 0, 0, 0);
        }
    }

    // epilogue: C/D layout col = l&15, row = (l>>4)*4 + reg
    #pragma unroll
    for (int i = 0; i < 4; ++i) {
        int rloc = m0 + (l >> 4) * 4 + i;
        int row = brow + rloc;
        if (row < N_) {
            float s = dinv[row];
            #pragma unroll
            for (int n = 0; n < 4; ++n) {
                ushort o = f2bf(s * acc[n][i]);
                outbf[(size_t)row * F_DIM + bcol + n * 16 + (l & 15)] = o;
            }
        }
    }
}

// ---------------- Gather-aggregate + bias + relu (bf16 messages) ----------------

__global__ __launch_bounds__(256) void gather_kernel(
    const ushort* __restrict__ Mbf, const int* __restrict__ row_ptr,
    const int* __restrict__ col_src, const float* __restrict__ dinv,
    const float* __restrict__ bias, float* __restrict__ Hout, int N_)
{
    int v = blockIdx.x * 4 + (threadIdx.x >> 6);
    if (v >= N_) return;
    int lane = threadIdx.x & 63;
    const uint* M1 = reinterpret_cast<const uint*>(Mbf);   // 2 bf16 per uint, row stride 64
    float accx, accy;
    { float a, b; bf2x(M1[(size_t)v * 64 + lane], a, b); accx = a; accy = b; }  // self loop
    int lo = row_ptr[v], hi = row_ptr[v + 1];
    int e = lo;
    for (; e + 8 <= hi; e += 8) {
        int s0 = col_src[e + 0], s1 = col_src[e + 1], s2 = col_src[e + 2], s3 = col_src[e + 3];
        int s4 = col_src[e + 4], s5 = col_src[e + 5], s6 = col_src[e + 6], s7 = col_src[e + 7];
        uint u0 = M1[(size_t)s0 * 64 + lane];
        uint u1 = M1[(size_t)s1 * 64 + lane];
        uint u2 = M1[(size_t)s2 * 64 + lane];
        uint u3 = M1[(size_t)s3 * 64 + lane];
        uint u4 = M1[(size_t)s4 * 64 + lane];
        uint u5 = M1[(size_t)s5 * 64 + lane];
        uint u6 = M1[(size_t)s6 * 64 + lane];
        uint u7 = M1[(size_t)s7 * 64 + lane];
        float a, b;
        bf2x(u0, a, b); accx += a; accy += b;
        bf2x(u1, a, b); accx += a; accy += b;
        bf2x(u2, a, b); accx += a; accy += b;
        bf2x(u3, a, b); accx += a; accy += b;
        bf2x(u4, a, b); accx += a; accy += b;
        bf2x(u5, a, b); accx += a; accy += b;
        bf2x(u6, a, b); accx += a; accy += b;
        bf2x(u7, a, b); accx += a; accy += b;
    }
    for (; e < hi; ++e) {
        float a, b; bf2x(M1[(size_t)col_src[e] * 64 + lane], a, b);
        accx += a; accy += b;
    }
    float dv = dinv[v];
    float2 bb = reinterpret_cast<const float2*>(bias)[lane];
    float2 o;
    o.x = fmaxf(dv * accx + bb.x, 0.0f);
    o.y = fmaxf(dv * accy + bb.y, 0.0f);
    reinterpret_cast<float2*>(Hout)[(size_t)v * 64 + lane] = o;
}

// ---------------- Mean-pool per graph + final linear (two-stage, deterministic) ----------------

__device__ __forceinline__ int lower_bound_i(const int* __restrict__ a, int n, int key) {
    int lo = 0, hi = n;
    while (lo < hi) {
        int mid = (lo + hi) >> 1;
        if (a[mid] < key) lo = mid + 1; else hi = mid;
    }
    return lo;
}

__global__ __launch_bounds__(128) void pool_part_kernel(
    const float* __restrict__ H, const int* __restrict__ batch,
    float* __restrict__ partial, int N_)
{
    int g = blockIdx.x / POOL_SEG;
    int s = blockIdx.x % POOL_SEG;
    int lo = lower_bound_i(batch, N_, g);
    int hi = lower_bound_i(batch, N_, g + 1);
    int len = hi - lo;
    int chunk = (len + POOL_SEG - 1) / POOL_SEG;
    int a = lo + s * chunk;
    int b = min(a + chunk, hi);
    int col = threadIdx.x;
    float acc = 0.f;
    for (int n = a; n < b; ++n) acc += H[(size_t)n * F_DIM + col];
    partial[((size_t)g * POOL_SEG + s) * F_DIM + col] = acc;
}

__global__ __launch_bounds__(128) void pool_final_kernel(
    const float* __restrict__ partial, const int* __restrict__ batch,
    const float* __restrict__ lin_w, const float* __restrict__ lin_b,
    float* __restrict__ out, int N_)
{
    int g = blockIdx.x;
    int col = threadIdx.x;
    float acc = 0.f;
    #pragma unroll
    for (int s = 0; s < POOL_SEG; ++s)
        acc += partial[((size_t)g * POOL_SEG + s) * F_DIM + col];
    int lo = lower_bound_i(batch, N_, g);
    int hi = lower_bound_i(batch, N_, g + 1);
    float pooled = acc / fmaxf((float)(hi - lo), 1.0f);
    float v = pooled * lin_w[col];
    __shared__ float sm[128];
    sm[col] = v;
    __syncthreads();
    if (col < 64) {
        float t = sm[col] + sm[col + 64];
        for (int off = 32; off; off >>= 1) t += __shfl_down(t, off);
        if (col == 0) out[g] = t + lin_b[0];
    }
}

// ---------------- Launch ----------------

extern "C" void kernel_launch(void* const* d_in, const int* in_sizes, int n_in,
                              void* d_out, int out_size, void* d_ws, size_t ws_size,
                              hipStream_t stream) {
    const float* x     = (const float*)d_in[0];
    const int*   ei    = (const int*)d_in[1];
    const int*   batch = (const int*)d_in[2];
    const float* W0    = (const float*)d_in[3];
    const float* b0    = (const float*)d_in[4];
    const float* W1    = (const float*)d_in[5];
    const float* b1    = (const float*)d_in[6];
    const float* W2    = (const float*)d_in[7];
    const float* b2    = (const float*)d_in[8];
    const float* lin_w = (const float*)d_in[9];
    const float* lin_b = (const float*)d_in[10];

    const int N_ = in_sizes[2];
    const int E_ = in_sizes[1] / 2;
    const int G_ = out_size;
    const int* esrc = ei;
    const int* edst = ei + E_;

    // workspace layout (bytes from d_ws)
    char* p = reinterpret_cast<char*>(d_ws);
    ushort* Mbf = reinterpret_cast<ushort*>(p);        p += (size_t)N_ * F_DIM * sizeof(ushort);
    float*  Hbuf = reinterpret_cast<float*>(p);        p += (size_t)N_ * F_DIM * sizeof(float);
    float*  dinvp = reinterpret_cast<float*>(p);       p += (size_t)N_ * sizeof(float);
    int*    deg = reinterpret_cast<int*>(p);           p += (size_t)N_ * sizeof(int);
    int*    row_ptr = reinterpret_cast<int*>(p);       p += (size_t)(N_ + 4) * sizeof(int);
    int*    rfill = reinterpret_cast<int*>(p);         p += (size_t)N_ * sizeof(int);
    int*    col_src = reinterpret_cast<int*>(p);       p += (size_t)E_ * sizeof(int);
    ushort* Wth = reinterpret_cast<ushort*>(p);        p += (size_t)3 * F_DIM * F_DIM * sizeof(ushort);
    ushort* Wtl = reinterpret_cast<ushort*>(p);        p += (size_t)3 * F_DIM * F_DIM * sizeof(ushort);
    float*  partial = reinterpret_cast<float*>(d_ws);  // alias Mbf region (dead during pooling)

    hipMemsetAsync(deg, 0, (size_t)N_ * sizeof(int), stream);

    int eb = (E_ + 255) / 256;
    wprep_kernel<<<48, 256, 0, stream>>>(W0, W1, W2, Wth, Wtl);
    count_kernel<<<eb, 256, 0, stream>>>(edst, deg, E_);
    scan_all_kernel<<<1, 1024, 0, stream>>>(deg, row_ptr, rfill, dinvp, N_, E_);
    fill_kernel<<<eb, 256, 0, stream>>>(esrc, edst, rfill, col_src, E_);

    const int gemm_grid = ((N_ + 63) / 64) * 2;
    const int gat_grid  = (N_ + 3) / 4;

    const float* cur_in = x;
    const float* bias[3] = {b0, b1, b2};
    for (int l = 0; l < 3; ++l) {
        gemm_scale_kernel<<<gemm_grid, 256, 0, stream>>>(
            cur_in, Wth + (size_t)l * F_DIM * F_DIM, Wtl + (size_t)l * F_DIM * F_DIM,
            dinvp, Mbf, N_);
        gather_kernel<<<gat_grid, 256, 0, stream>>>(Mbf, row_ptr, col_src, dinvp, bias[l], Hbuf, N_);
        cur_in = Hbuf;
    }

    pool_part_kernel<<<G_ * POOL_SEG, 128, 0, stream>>>(Hbuf, batch, partial, N_);
    pool_final_kernel<<<G_, 128, 0, stream>>>(partial, batch, lin_w, lin_b, (float*)d_out, N_);
}

// Round 5
// 280.071 us; speedup vs baseline: 1.0141x; 1.0141x over previous
//
#include <hip/hip_runtime.h>
#include <hip/hip_bf16.h>

#define F_DIM 128
#define POOL_SEG 16

typedef __attribute__((ext_vector_type(8))) short short8v;   // 8 bf16
typedef __attribute__((ext_vector_type(4))) float float4v;   // MFMA acc

// ---------------- helpers ----------------

__device__ __forceinline__ ushort f2bf(float f) {  // RNE f32 -> bf16
    uint u = __float_as_uint(f);
    u += 0x7fffu + ((u >> 16) & 1u);
    return (ushort)(u >> 16);
}
__device__ __forceinline__ float bf2f(ushort h) {
    return __uint_as_float(((uint)h) << 16);
}
__device__ __forceinline__ void bf2x(uint u, float& a, float& b) {
    a = __uint_as_float((u & 0x0000ffffu) << 16);
    b = __uint_as_float(u & 0xffff0000u);
}

// ---------------- CSR build ----------------

__global__ void count_kernel(const int* __restrict__ dst, int* __restrict__ deg, int E_) {
    int i = blockIdx.x * blockDim.x + threadIdx.x;
    if (i < E_) atomicAdd(&deg[dst[i]], 1);
}

__global__ void scan_blocksums_kernel(const int* __restrict__ deg, int* __restrict__ bsum, int N_) {
    __shared__ int s[256];
    int i = blockIdx.x * 256 + threadIdx.x;
    s[threadIdx.x] = (i < N_) ? deg[i] : 0;
    __syncthreads();
    for (int off = 128; off; off >>= 1) {
        if (threadIdx.x < off) s[threadIdx.x] += s[threadIdx.x + off];
        __syncthreads();
    }
    if (threadIdx.x == 0) bsum[blockIdx.x] = s[0];
}

__global__ void scan_bs_kernel(const int* __restrict__ bsum, int* __restrict__ bsx, int NB) {
    __shared__ int s[256];
    int t = threadIdx.x;
    int orig = (t < NB) ? bsum[t] : 0;
    s[t] = orig;
    __syncthreads();
    for (int off = 1; off < 256; off <<= 1) {
        int v = (t >= off) ? s[t - off] : 0;
        __syncthreads();
        s[t] += v;
        __syncthreads();
    }
    if (t < NB) bsx[t] = s[t] - orig;   // exclusive
}

__global__ void scan_final_kernel(const int* __restrict__ deg, const int* __restrict__ bsx,
                                  int* __restrict__ row_ptr, int* __restrict__ rfill,
                                  float* __restrict__ dinv, int N_, int E_) {
    __shared__ int s[256];
    int t = threadIdx.x;
    int i = blockIdx.x * 256 + t;
    int orig = (i < N_) ? deg[i] : 0;
    s[t] = orig;
    __syncthreads();
    for (int off = 1; off < 256; off <<= 1) {
        int v = (t >= off) ? s[t - off] : 0;
        __syncthreads();
        s[t] += v;
        __syncthreads();
    }
    int excl = s[t] - orig + bsx[blockIdx.x];
    if (i < N_) {
        row_ptr[i] = excl;
        rfill[i] = excl;
        dinv[i] = 1.0f / sqrtf((float)(orig + 1));   // +1 self-loop
    }
    if (i == N_ - 1) row_ptr[N_] = E_;
}

__global__ void fill_kernel(const int* __restrict__ src, const int* __restrict__ dst,
                            int* __restrict__ cur, int* __restrict__ col_src, int E_) {
    int i = blockIdx.x * blockDim.x + threadIdx.x;
    if (i < E_) {
        int p = atomicAdd(&cur[dst[i]], 1);
        col_src[p] = src[i];
    }
}

// ---------------- W^T prep: Wt[hi/lo][layer][c][k] = split(W[k][c]) ----------------

__global__ __launch_bounds__(256) void wprep_kernel(
    const float* __restrict__ W0, const float* __restrict__ W1, const float* __restrict__ W2,
    ushort* __restrict__ Wth, ushort* __restrict__ Wtl)
{
    int layer = blockIdx.x >> 4;
    int chunkc = blockIdx.x & 15;
    const float* W = (layer == 0) ? W0 : (layer == 1) ? W1 : W2;
    int t = threadIdx.x;
    int c  = chunkc * 8 + (t >> 5);      // column of W
    int k0 = (t & 31) * 4;               // 4 consecutive k
    ushort4 hi, lo;
    float v0 = W[(size_t)(k0 + 0) * F_DIM + c];
    float v1 = W[(size_t)(k0 + 1) * F_DIM + c];
    float v2 = W[(size_t)(k0 + 2) * F_DIM + c];
    float v3 = W[(size_t)(k0 + 3) * F_DIM + c];
    hi.x = f2bf(v0); lo.x = f2bf(v0 - bf2f(hi.x));
    hi.y = f2bf(v1); lo.y = f2bf(v1 - bf2f(hi.y));
    hi.z = f2bf(v2); lo.z = f2bf(v2 - bf2f(hi.z));
    hi.w = f2bf(v3); lo.w = f2bf(v3 - bf2f(hi.w));
    size_t o = (size_t)layer * F_DIM * F_DIM + (size_t)c * F_DIM + k0;
    *reinterpret_cast<ushort4*>(&Wth[o]) = hi;
    *reinterpret_cast<ushort4*>(&Wtl[o]) = lo;
}

// ---------------- MFMA GEMM: M[r][c] = bf16( dinv[r] * sum_k in[r][k] * W[k][c] ) ----------------
// bf16 hi/lo split, 3-term -> ~f32 accuracy. Output into split half-feature buffers.

__global__ __launch_bounds__(256) void gemm_scale_kernel(
    const float* __restrict__ in, const ushort* __restrict__ Wth, const ushort* __restrict__ Wtl,
    const float* __restrict__ dinv, ushort* __restrict__ outA, ushort* __restrict__ outB, int N_)
{
    __shared__ ushort Ah[64 * F_DIM];   // 16 KB each, XOR-swizzled k within row
    __shared__ ushort Al[64 * F_DIM];
    __shared__ ushort Bh[64 * F_DIM];   // [c][k]
    __shared__ ushort Bl[64 * F_DIM];

    const int tid = threadIdx.x;
    const int brow = (blockIdx.x >> 1) * 64;
    const int bcol = (blockIdx.x & 1) * 64;

    #pragma unroll
    for (int i = 0; i < 4; ++i) {
        int chunk = tid + i * 256;
        int r  = chunk >> 4;
        int k0 = (chunk & 15) * 8;
        int row = brow + r;
        float f[8];
        if (row < N_) {
            float4 g0 = *reinterpret_cast<const float4*>(&in[(size_t)row * F_DIM + k0]);
            float4 g1 = *reinterpret_cast<const float4*>(&in[(size_t)row * F_DIM + k0 + 4]);
            f[0] = g0.x; f[1] = g0.y; f[2] = g0.z; f[3] = g0.w;
            f[4] = g1.x; f[5] = g1.y; f[6] = g1.z; f[7] = g1.w;
        } else {
            #pragma unroll
            for (int j = 0; j < 8; ++j) f[j] = 0.f;
        }
        ushort hi[8], lo[8];
        #pragma unroll
        for (int j = 0; j < 8; ++j) {
            hi[j] = f2bf(f[j]);
            lo[j] = f2bf(f[j] - bf2f(hi[j]));
        }
        int idx = r * F_DIM + (k0 ^ ((r & 7) << 3));
        *reinterpret_cast<short8v*>(&Ah[idx]) = *reinterpret_cast<short8v*>(hi);
        *reinterpret_cast<short8v*>(&Al[idx]) = *reinterpret_cast<short8v*>(lo);
    }
    #pragma unroll
    for (int i = 0; i < 4; ++i) {
        int chunk = tid + i * 256;
        int c  = chunk >> 4;
        int k0 = (chunk & 15) * 8;
        size_t go = (size_t)(bcol + c) * F_DIM + k0;
        int idx = c * F_DIM + (k0 ^ ((c & 7) << 3));
        *reinterpret_cast<short8v*>(&Bh[idx]) = *reinterpret_cast<const short8v*>(&Wth[go]);
        *reinterpret_cast<short8v*>(&Bl[idx]) = *reinterpret_cast<const short8v*>(&Wtl[go]);
    }
    __syncthreads();

    const int l = tid & 63;
    const int wave = tid >> 6;
    const int m0 = wave * 16;
    const int row_a = m0 + (l & 15);
    const int kgrp = (l >> 4) * 8;
    const int aswz = (row_a & 7) << 3;

    float4v acc[4] = {{0.f,0.f,0.f,0.f},{0.f,0.f,0.f,0.f},{0.f,0.f,0.f,0.f},{0.f,0.f,0.f,0.f}};

    #pragma unroll
    for (int kk = 0; kk < 4; ++kk) {
        int kbase = kk * 32 + kgrp;
        short8v a_h = *reinterpret_cast<short8v*>(&Ah[row_a * F_DIM + (kbase ^ aswz)]);
        short8v a_l = *reinterpret_cast<short8v*>(&Al[row_a * F_DIM + (kbase ^ aswz)]);
        #pragma unroll
        for (int n = 0; n < 4; ++n) {
            int col_b = n * 16 + (l & 15);
            int bidx = col_b * F_DIM + (kbase ^ ((col_b & 7) << 3));
            short8v b_h = *reinterpret_cast<short8v*>(&Bh[bidx]);
            short8v b_l = *reinterpret_cast<short8v*>(&Bl[bidx]);
            acc[n] = __builtin_amdgcn_mfma_f32_16x16x32_bf16(a_h, b_h, acc[n], 0, 0, 0);
            acc[n] = __builtin_amdgcn_mfma_f32_16x16x32_bf16(a_l, b_h, acc[n], 0, 0, 0);
            acc[n] = __builtin_amdgcn_mfma_f32_16x16x32_bf16(a_h, b_l, acc[n], 0, 0, 0);
        }
    }

    ushort* outp = (bcol == 0) ? outA : outB;   // half-feature buffer, row stride 64
    #pragma unroll
    for (int i = 0; i < 4; ++i) {
        int rloc = m0 + (l >> 4) * 4 + i;
        int row = brow + rloc;
        if (row < N_) {
            float s = dinv[row];
            #pragma unroll
            for (int n = 0; n < 4; ++n) {
                ushort o = f2bf(s * acc[n][i]);
                outp[(size_t)row * 64 + n * 16 + (l & 15)] = o;
            }
        }
    }
}

// ---------------- Gather-aggregate + bias + relu (bf16, half-feature passes) ----------------
// grid (ceil(N/4), 2): y = feature half. One wave per node; lanes 0-31 / 32-63
// process two edges at once (same node, no divergence); combine via shfl_xor(32).

__global__ __launch_bounds__(256) void gather_kernel(
    const ushort* __restrict__ MA, const ushort* __restrict__ MB,
    const int* __restrict__ row_ptr, const int* __restrict__ col_src,
    const float* __restrict__ dinv, const float* __restrict__ bias,
    float* __restrict__ Hout, int N_)
{
    int v = blockIdx.x * 4 + (threadIdx.x >> 6);
    if (v >= N_) return;
    const int pass = blockIdx.y;
    const uint* M1 = reinterpret_cast<const uint*>(pass ? MB : MA);   // row stride 32 uints
    const int lane = threadIdx.x & 63;
    const int fl = lane & 31;       // feature uint (2 bf16)
    const int half = lane >> 5;     // which of the 2 concurrent edges

    float accx = 0.f, accy = 0.f;
    if (half == 0) {  // self loop counted once
        float a, b; bf2x(M1[(size_t)v * 32 + fl], a, b);
        accx = a; accy = b;
    }
    int lo = row_ptr[v], hi = row_ptr[v + 1];
    int e = lo;
    for (; e + 8 <= hi; e += 8) {
        int i0 = e + half;
        int s0 = col_src[i0 + 0];
        int s1 = col_src[i0 + 2];
        int s2 = col_src[i0 + 4];
        int s3 = col_src[i0 + 6];
        uint u0 = M1[(size_t)s0 * 32 + fl];
        uint u1 = M1[(size_t)s1 * 32 + fl];
        uint u2 = M1[(size_t)s2 * 32 + fl];
        uint u3 = M1[(size_t)s3 * 32 + fl];
        float a, b;
        bf2x(u0, a, b); accx += a; accy += b;
        bf2x(u1, a, b); accx += a; accy += b;
        bf2x(u2, a, b); accx += a; accy += b;
        bf2x(u3, a, b); accx += a; accy += b;
    }
    for (; e < hi; e += 2) {
        int idx = e + half;
        if (idx < hi) {
            float a, b; bf2x(M1[(size_t)col_src[idx] * 32 + fl], a, b);
            accx += a; accy += b;
        }
    }
    accx += __shfl_xor(accx, 32);
    accy += __shfl_xor(accy, 32);

    if (half == 0) {
        float dv = dinv[v];
        float2 bb = reinterpret_cast<const float2*>(bias)[pass * 32 + fl];
        float2 o;
        o.x = fmaxf(dv * accx + bb.x, 0.0f);
        o.y = fmaxf(dv * accy + bb.y, 0.0f);
        reinterpret_cast<float2*>(Hout)[(size_t)v * 64 + pass * 32 + fl] = o;
    }
}

// ---------------- Mean-pool per graph + final linear (two-stage, deterministic) ----------------

__device__ __forceinline__ int lower_bound_i(const int* __restrict__ a, int n, int key) {
    int lo = 0, hi = n;
    while (lo < hi) {
        int mid = (lo + hi) >> 1;
        if (a[mid] < key) lo = mid + 1; else hi = mid;
    }
    return lo;
}

__global__ __launch_bounds__(128) void pool_part_kernel(
    const float* __restrict__ H, const int* __restrict__ batch,
    float* __restrict__ partial, int N_)
{
    int g = blockIdx.x / POOL_SEG;
    int s = blockIdx.x % POOL_SEG;
    int lo = lower_bound_i(batch, N_, g);
    int hi = lower_bound_i(batch, N_, g + 1);
    int len = hi - lo;
    int chunk = (len + POOL_SEG - 1) / POOL_SEG;
    int a = lo + s * chunk;
    int b = min(a + chunk, hi);
    int col = threadIdx.x;
    float acc = 0.f;
    for (int n = a; n < b; ++n) acc += H[(size_t)n * F_DIM + col];
    partial[((size_t)g * POOL_SEG + s) * F_DIM + col] = acc;
}

__global__ __launch_bounds__(128) void pool_final_kernel(
    const float* __restrict__ partial, const int* __restrict__ batch,
    const float* __restrict__ lin_w, const float* __restrict__ lin_b,
    float* __restrict__ out, int N_)
{
    int g = blockIdx.x;
    int col = threadIdx.x;
    float acc = 0.f;
    #pragma unroll
    for (int s = 0; s < POOL_SEG; ++s)
        acc += partial[((size_t)g * POOL_SEG + s) * F_DIM + col];
    int lo = lower_bound_i(batch, N_, g);
    int hi = lower_bound_i(batch, N_, g + 1);
    float pooled = acc / fmaxf((float)(hi - lo), 1.0f);
    float v = pooled * lin_w[col];
    __shared__ float sm[128];
    sm[col] = v;
    __syncthreads();
    if (col < 64) {
        float t = sm[col] + sm[col + 64];
        for (int off = 32; off; off >>= 1) t += __shfl_down(t, off);
        if (col == 0) out[g] = t + lin_b[0];
    }
}

// ---------------- Launch ----------------

extern "C" void kernel_launch(void* const* d_in, const int* in_sizes, int n_in,
                              void* d_out, int out_size, void* d_ws, size_t ws_size,
                              hipStream_t stream) {
    const float* x     = (const float*)d_in[0];
    const int*   ei    = (const int*)d_in[1];
    const int*   batch = (const int*)d_in[2];
    const float* W0    = (const float*)d_in[3];
    const float* b0    = (const float*)d_in[4];
    const float* W1    = (const float*)d_in[5];
    const float* b1    = (const float*)d_in[6];
    const float* W2    = (const float*)d_in[7];
    const float* b2    = (const float*)d_in[8];
    const float* lin_w = (const float*)d_in[9];
    const float* lin_b = (const float*)d_in[10];

    const int N_ = in_sizes[2];
    const int E_ = in_sizes[1] / 2;
    const int G_ = out_size;
    const int* esrc = ei;
    const int* edst = ei + E_;

    // workspace layout (bytes from d_ws)
    char* p = reinterpret_cast<char*>(d_ws);
    ushort* MA = reinterpret_cast<ushort*>(p);         p += (size_t)N_ * 64 * sizeof(ushort);
    ushort* MB = reinterpret_cast<ushort*>(p);         p += (size_t)N_ * 64 * sizeof(ushort);
    float*  Hbuf = reinterpret_cast<float*>(p);        p += (size_t)N_ * F_DIM * sizeof(float);
    float*  dinvp = reinterpret_cast<float*>(p);       p += (size_t)N_ * sizeof(float);
    int*    deg = reinterpret_cast<int*>(p);           p += (size_t)N_ * sizeof(int);
    int*    row_ptr = reinterpret_cast<int*>(p);       p += (size_t)(N_ + 4) * sizeof(int);
    int*    rfill = reinterpret_cast<int*>(p);         p += (size_t)N_ * sizeof(int);
    int*    col_src = reinterpret_cast<int*>(p);       p += (size_t)E_ * sizeof(int);
    ushort* Wth = reinterpret_cast<ushort*>(p);        p += (size_t)3 * F_DIM * F_DIM * sizeof(ushort);
    ushort* Wtl = reinterpret_cast<ushort*>(p);        p += (size_t)3 * F_DIM * F_DIM * sizeof(ushort);
    const int NB = (N_ + 255) / 256;
    int*    bsum = reinterpret_cast<int*>(p);          p += (size_t)NB * sizeof(int);
    int*    bsx = reinterpret_cast<int*>(p);
    float*  partial = reinterpret_cast<float*>(d_ws);  // alias MA/MB region (dead during pooling)

    hipMemsetAsync(deg, 0, (size_t)N_ * sizeof(int), stream);

    int eb = (E_ + 255) / 256;
    wprep_kernel<<<48, 256, 0, stream>>>(W0, W1, W2, Wth, Wtl);
    count_kernel<<<eb, 256, 0, stream>>>(edst, deg, E_);
    scan_blocksums_kernel<<<NB, 256, 0, stream>>>(deg, bsum, N_);
    scan_bs_kernel<<<1, 256, 0, stream>>>(bsum, bsx, NB);
    scan_final_kernel<<<NB, 256, 0, stream>>>(deg, bsx, row_ptr, rfill, dinvp, N_, E_);
    fill_kernel<<<eb, 256, 0, stream>>>(esrc, edst, rfill, col_src, E_);

    const int gemm_grid = ((N_ + 63) / 64) * 2;
    const int gat_x = (N_ + 3) / 4;

    const float* cur_in = x;
    const float* bias[3] = {b0, b1, b2};
    for (int l = 0; l < 3; ++l) {
        gemm_scale_kernel<<<gemm_grid, 256, 0, stream>>>(
            cur_in, Wth + (size_t)l * F_DIM * F_DIM, Wtl + (size_t)l * F_DIM * F_DIM,
            dinvp, MA, MB, N_);
        gather_kernel<<<dim3(gat_x, 2), 256, 0, stream>>>(
            MA, MB, row_ptr, col_src, dinvp, bias[l], Hbuf, N_);
        cur_in = Hbuf;
    }

    pool_part_kernel<<<G_ * POOL_SEG, 128, 0, stream>>>(Hbuf, batch, partial, N_);
    pool_final_kernel<<<G_, 128, 0, stream>>>(partial, batch, lin_w, lin_b, (float*)d_out, N_);
}

// Round 6
// 228.156 us; speedup vs baseline: 1.2448x; 1.2275x over previous
//
#include <hip/hip_runtime.h>
#include <hip/hip_bf16.h>

#define F_DIM 128
#define POOL_SEG 16

typedef __attribute__((ext_vector_type(8))) short short8v;   // 8 bf16
typedef __attribute__((ext_vector_type(4))) float float4v;   // MFMA acc

// ---------------- helpers ----------------

__device__ __forceinline__ ushort f2bf(float f) {  // RNE f32 -> bf16
    uint u = __float_as_uint(f);
    u += 0x7fffu + ((u >> 16) & 1u);
    return (ushort)(u >> 16);
}
__device__ __forceinline__ float bf2f(ushort h) {
    return __uint_as_float(((uint)h) << 16);
}
__device__ __forceinline__ void bf2x(uint u, float& a, float& b) {
    a = __uint_as_float((u & 0x0000ffffu) << 16);
    b = __uint_as_float(u & 0xffff0000u);
}

// ---------------- CSR build ----------------

__global__ void count_kernel(const int* __restrict__ dst, int* __restrict__ deg, int E_) {
    int i = blockIdx.x * blockDim.x + threadIdx.x;
    if (i < E_) atomicAdd(&deg[dst[i]], 1);
}

__global__ void scan_blocksums_kernel(const int* __restrict__ deg, int* __restrict__ bsum, int N_) {
    __shared__ int s[256];
    int i = blockIdx.x * 256 + threadIdx.x;
    s[threadIdx.x] = (i < N_) ? deg[i] : 0;
    __syncthreads();
    for (int off = 128; off; off >>= 1) {
        if (threadIdx.x < off) s[threadIdx.x] += s[threadIdx.x + off];
        __syncthreads();
    }
    if (threadIdx.x == 0) bsum[blockIdx.x] = s[0];
}

__global__ void scan_bs_kernel(const int* __restrict__ bsum, int* __restrict__ bsx, int NB) {
    __shared__ int s[256];
    int t = threadIdx.x;
    int orig = (t < NB) ? bsum[t] : 0;
    s[t] = orig;
    __syncthreads();
    for (int off = 1; off < 256; off <<= 1) {
        int v = (t >= off) ? s[t - off] : 0;
        __syncthreads();
        s[t] += v;
        __syncthreads();
    }
    if (t < NB) bsx[t] = s[t] - orig;   // exclusive
}

__global__ void scan_final_kernel(const int* __restrict__ deg, const int* __restrict__ bsx,
                                  int* __restrict__ row_ptr, int* __restrict__ rfill,
                                  float* __restrict__ dinv, int N_, int E_) {
    __shared__ int s[256];
    int t = threadIdx.x;
    int i = blockIdx.x * 256 + t;
    int orig = (i < N_) ? deg[i] : 0;
    s[t] = orig;
    __syncthreads();
    for (int off = 1; off < 256; off <<= 1) {
        int v = (t >= off) ? s[t - off] : 0;
        __syncthreads();
        s[t] += v;
        __syncthreads();
    }
    int excl = s[t] - orig + bsx[blockIdx.x];
    if (i < N_) {
        row_ptr[i] = excl;
        rfill[i] = excl;
        dinv[i] = 1.0f / sqrtf((float)(orig + 1));   // +1 self-loop
    }
    if (i == N_ - 1) row_ptr[N_] = E_;
}

__global__ void fill_kernel(const int* __restrict__ src, const int* __restrict__ dst,
                            int* __restrict__ cur, int* __restrict__ col_src, int E_) {
    int i = blockIdx.x * blockDim.x + threadIdx.x;
    if (i < E_) {
        int p = atomicAdd(&cur[dst[i]], 1);
        col_src[p] = src[i];
    }
}

// ---------------- W^T prep: Wt[hi/lo][layer][c][k] = split(W[k][c]) ----------------

__global__ __launch_bounds__(256) void wprep_kernel(
    const float* __restrict__ W0, const float* __restrict__ W1, const float* __restrict__ W2,
    ushort* __restrict__ Wth, ushort* __restrict__ Wtl)
{
    int layer = blockIdx.x >> 4;
    int chunkc = blockIdx.x & 15;
    const float* W = (layer == 0) ? W0 : (layer == 1) ? W1 : W2;
    int t = threadIdx.x;
    int c  = chunkc * 8 + (t >> 5);      // column of W
    int k0 = (t & 31) * 4;               // 4 consecutive k
    ushort4 hi, lo;
    float v0 = W[(size_t)(k0 + 0) * F_DIM + c];
    float v1 = W[(size_t)(k0 + 1) * F_DIM + c];
    float v2 = W[(size_t)(k0 + 2) * F_DIM + c];
    float v3 = W[(size_t)(k0 + 3) * F_DIM + c];
    hi.x = f2bf(v0); lo.x = f2bf(v0 - bf2f(hi.x));
    hi.y = f2bf(v1); lo.y = f2bf(v1 - bf2f(hi.y));
    hi.z = f2bf(v2); lo.z = f2bf(v2 - bf2f(hi.z));
    hi.w = f2bf(v3); lo.w = f2bf(v3 - bf2f(hi.w));
    size_t o = (size_t)layer * F_DIM * F_DIM + (size_t)c * F_DIM + k0;
    *reinterpret_cast<ushort4*>(&Wth[o]) = hi;
    *reinterpret_cast<ushort4*>(&Wtl[o]) = lo;
}

// ---------------- MFMA GEMM: Mbf[r][c] = bf16( dinv[r] * sum_k in[r][k] * W[k][c] ) ----------------
// bf16 hi/lo split, 3-term (AhBh + AlBh + AhBl) -> ~f32 accuracy.

__global__ __launch_bounds__(256) void gemm_scale_kernel(
    const float* __restrict__ in, const ushort* __restrict__ Wth, const ushort* __restrict__ Wtl,
    const float* __restrict__ dinv, ushort* __restrict__ outbf, int N_)
{
    __shared__ ushort Ah[64 * F_DIM];   // 16 KB each, XOR-swizzled k within row
    __shared__ ushort Al[64 * F_DIM];
    __shared__ ushort Bh[64 * F_DIM];   // [c][k]
    __shared__ ushort Bl[64 * F_DIM];

    const int tid = threadIdx.x;
    const int brow = (blockIdx.x >> 1) * 64;
    const int bcol = (blockIdx.x & 1) * 64;

    #pragma unroll
    for (int i = 0; i < 4; ++i) {
        int chunk = tid + i * 256;
        int r  = chunk >> 4;
        int k0 = (chunk & 15) * 8;
        int row = brow + r;
        float f[8];
        if (row < N_) {
            float4 g0 = *reinterpret_cast<const float4*>(&in[(size_t)row * F_DIM + k0]);
            float4 g1 = *reinterpret_cast<const float4*>(&in[(size_t)row * F_DIM + k0 + 4]);
            f[0] = g0.x; f[1] = g0.y; f[2] = g0.z; f[3] = g0.w;
            f[4] = g1.x; f[5] = g1.y; f[6] = g1.z; f[7] = g1.w;
        } else {
            #pragma unroll
            for (int j = 0; j < 8; ++j) f[j] = 0.f;
        }
        ushort hi[8], lo[8];
        #pragma unroll
        for (int j = 0; j < 8; ++j) {
            hi[j] = f2bf(f[j]);
            lo[j] = f2bf(f[j] - bf2f(hi[j]));
        }
        int idx = r * F_DIM + (k0 ^ ((r & 7) << 3));
        *reinterpret_cast<short8v*>(&Ah[idx]) = *reinterpret_cast<short8v*>(hi);
        *reinterpret_cast<short8v*>(&Al[idx]) = *reinterpret_cast<short8v*>(lo);
    }
    #pragma unroll
    for (int i = 0; i < 4; ++i) {
        int chunk = tid + i * 256;
        int c  = chunk >> 4;
        int k0 = (chunk & 15) * 8;
        size_t go = (size_t)(bcol + c) * F_DIM + k0;
        int idx = c * F_DIM + (k0 ^ ((c & 7) << 3));
        *reinterpret_cast<short8v*>(&Bh[idx]) = *reinterpret_cast<const short8v*>(&Wth[go]);
        *reinterpret_cast<short8v*>(&Bl[idx]) = *reinterpret_cast<const short8v*>(&Wtl[go]);
    }
    __syncthreads();

    const int l = tid & 63;
    const int wave = tid >> 6;
    const int m0 = wave * 16;
    const int row_a = m0 + (l & 15);
    const int kgrp = (l >> 4) * 8;
    const int aswz = (row_a & 7) << 3;

    float4v acc[4] = {{0.f,0.f,0.f,0.f},{0.f,0.f,0.f,0.f},{0.f,0.f,0.f,0.f},{0.f,0.f,0.f,0.f}};

    #pragma unroll
    for (int kk = 0; kk < 4; ++kk) {
        int kbase = kk * 32 + kgrp;
        short8v a_h = *reinterpret_cast<short8v*>(&Ah[row_a * F_DIM + (kbase ^ aswz)]);
        short8v a_l = *reinterpret_cast<short8v*>(&Al[row_a * F_DIM + (kbase ^ aswz)]);
        #pragma unroll
        for (int n = 0; n < 4; ++n) {
            int col_b = n * 16 + (l & 15);
            int bidx = col_b * F_DIM + (kbase ^ ((col_b & 7) << 3));
            short8v b_h = *reinterpret_cast<short8v*>(&Bh[bidx]);
            short8v b_l = *reinterpret_cast<short8v*>(&Bl[bidx]);
            acc[n] = __builtin_amdgcn_mfma_f32_16x16x32_bf16(a_h, b_h, acc[n], 0, 0, 0);
            acc[n] = __builtin_amdgcn_mfma_f32_16x16x32_bf16(a_l, b_h, acc[n], 0, 0, 0);
            acc[n] = __builtin_amdgcn_mfma_f32_16x16x32_bf16(a_h, b_l, acc[n], 0, 0, 0);
        }
    }

    #pragma unroll
    for (int i = 0; i < 4; ++i) {
        int rloc = m0 + (l >> 4) * 4 + i;
        int row = brow + rloc;
        if (row < N_) {
            float s = dinv[row];
            #pragma unroll
            for (int n = 0; n < 4; ++n) {
                ushort o = f2bf(s * acc[n][i]);
                outbf[(size_t)row * F_DIM + bcol + n * 16 + (l & 15)] = o;
            }
        }
    }
}

// ---------------- Gather-aggregate + bias + relu (bf16, uint4 loads) ----------------
// One wave per node (4/block). 16 lanes per edge-slot x uint4 (16B) = full 256B row
// per slot; 4 edges per wave-load. Reduce across slots with shfl_xor(16/32).

__global__ __launch_bounds__(256) void gather_kernel(
    const ushort* __restrict__ Mbf, const int* __restrict__ row_ptr,
    const int* __restrict__ col_src, const float* __restrict__ dinv,
    const float* __restrict__ bias, float* __restrict__ Hout, int N_)
{
    int v = blockIdx.x * 4 + (threadIdx.x >> 6);
    if (v >= N_) return;
    const int lane = threadIdx.x & 63;
    const int fq  = lane & 15;      // uint4 index within row (16 x 16B = 256B)
    const int sub = lane >> 4;      // edge slot 0..3
    const uint4* M4 = reinterpret_cast<const uint4*>(Mbf);   // row stride 16

    float acc[8];
    if (sub == 0) {   // self loop counted once
        uint4 u = M4[(size_t)v * 16 + fq];
        bf2x(u.x, acc[0], acc[1]);
        bf2x(u.y, acc[2], acc[3]);
        bf2x(u.z, acc[4], acc[5]);
        bf2x(u.w, acc[6], acc[7]);
    } else {
        #pragma unroll
        for (int j = 0; j < 8; ++j) acc[j] = 0.f;
    }

    int lo = row_ptr[v], hi = row_ptr[v + 1];
    int e = lo;
    for (; e + 12 <= hi; e += 12) {
        int s0 = col_src[e + sub];
        int s1 = col_src[e + 4 + sub];
        int s2 = col_src[e + 8 + sub];
        uint4 u0 = M4[(size_t)s0 * 16 + fq];
        uint4 u1 = M4[(size_t)s1 * 16 + fq];
        uint4 u2 = M4[(size_t)s2 * 16 + fq];
        float a, b;
        bf2x(u0.x, a, b); acc[0] += a; acc[1] += b;
        bf2x(u0.y, a, b); acc[2] += a; acc[3] += b;
        bf2x(u0.z, a, b); acc[4] += a; acc[5] += b;
        bf2x(u0.w, a, b); acc[6] += a; acc[7] += b;
        bf2x(u1.x, a, b); acc[0] += a; acc[1] += b;
        bf2x(u1.y, a, b); acc[2] += a; acc[3] += b;
        bf2x(u1.z, a, b); acc[4] += a; acc[5] += b;
        bf2x(u1.w, a, b); acc[6] += a; acc[7] += b;
        bf2x(u2.x, a, b); acc[0] += a; acc[1] += b;
        bf2x(u2.y, a, b); acc[2] += a; acc[3] += b;
        bf2x(u2.z, a, b); acc[4] += a; acc[5] += b;
        bf2x(u2.w, a, b); acc[6] += a; acc[7] += b;
    }
    for (; e + 4 <= hi; e += 4) {
        int s = col_src[e + sub];
        uint4 u = M4[(size_t)s * 16 + fq];
        float a, b;
        bf2x(u.x, a, b); acc[0] += a; acc[1] += b;
        bf2x(u.y, a, b); acc[2] += a; acc[3] += b;
        bf2x(u.z, a, b); acc[4] += a; acc[5] += b;
        bf2x(u.w, a, b); acc[6] += a; acc[7] += b;
    }
    if (e + sub < hi) {   // tail 0..3 edges
        int s = col_src[e + sub];
        uint4 u = M4[(size_t)s * 16 + fq];
        float a, b;
        bf2x(u.x, a, b); acc[0] += a; acc[1] += b;
        bf2x(u.y, a, b); acc[2] += a; acc[3] += b;
        bf2x(u.z, a, b); acc[4] += a; acc[5] += b;
        bf2x(u.w, a, b); acc[6] += a; acc[7] += b;
    }

    #pragma unroll
    for (int j = 0; j < 8; ++j) {
        acc[j] += __shfl_xor(acc[j], 16);
        acc[j] += __shfl_xor(acc[j], 32);
    }

    if (sub == 0) {
        float dv = dinv[v];
        const float4* b4 = reinterpret_cast<const float4*>(bias);
        float4 bb0 = b4[fq * 2], bb1 = b4[fq * 2 + 1];
        float4 o0, o1;
        o0.x = fmaxf(dv * acc[0] + bb0.x, 0.0f);
        o0.y = fmaxf(dv * acc[1] + bb0.y, 0.0f);
        o0.z = fmaxf(dv * acc[2] + bb0.z, 0.0f);
        o0.w = fmaxf(dv * acc[3] + bb0.w, 0.0f);
        o1.x = fmaxf(dv * acc[4] + bb1.x, 0.0f);
        o1.y = fmaxf(dv * acc[5] + bb1.y, 0.0f);
        o1.z = fmaxf(dv * acc[6] + bb1.z, 0.0f);
        o1.w = fmaxf(dv * acc[7] + bb1.w, 0.0f);
        float4* H4 = reinterpret_cast<float4*>(&Hout[(size_t)v * F_DIM + fq * 8]);
        H4[0] = o0;
        H4[1] = o1;
    }
}

// ---------------- Mean-pool per graph + final linear (two-stage, deterministic) ----------------

__device__ __forceinline__ int lower_bound_i(const int* __restrict__ a, int n, int key) {
    int lo = 0, hi = n;
    while (lo < hi) {
        int mid = (lo + hi) >> 1;
        if (a[mid] < key) lo = mid + 1; else hi = mid;
    }
    return lo;
}

__global__ __launch_bounds__(128) void pool_part_kernel(
    const float* __restrict__ H, const int* __restrict__ batch,
    float* __restrict__ partial, int N_)
{
    int g = blockIdx.x / POOL_SEG;
    int s = blockIdx.x % POOL_SEG;
    int lo = lower_bound_i(batch, N_, g);
    int hi = lower_bound_i(batch, N_, g + 1);
    int len = hi - lo;
    int chunk = (len + POOL_SEG - 1) / POOL_SEG;
    int a = lo + s * chunk;
    int b = min(a + chunk, hi);
    int col = threadIdx.x;
    float acc = 0.f;
    for (int n = a; n < b; ++n) acc += H[(size_t)n * F_DIM + col];
    partial[((size_t)g * POOL_SEG + s) * F_DIM + col] = acc;
}

__global__ __launch_bounds__(128) void pool_final_kernel(
    const float* __restrict__ partial, const int* __restrict__ batch,
    const float* __restrict__ lin_w, const float* __restrict__ lin_b,
    float* __restrict__ out, int N_)
{
    int g = blockIdx.x;
    int col = threadIdx.x;
    float acc = 0.f;
    #pragma unroll
    for (int s = 0; s < POOL_SEG; ++s)
        acc += partial[((size_t)g * POOL_SEG + s) * F_DIM + col];
    int lo = lower_bound_i(batch, N_, g);
    int hi = lower_bound_i(batch, N_, g + 1);
    float pooled = acc / fmaxf((float)(hi - lo), 1.0f);
    float v = pooled * lin_w[col];
    __shared__ float sm[128];
    sm[col] = v;
    __syncthreads();
    if (col < 64) {
        float t = sm[col] + sm[col + 64];
        for (int off = 32; off; off >>= 1) t += __shfl_down(t, off);
        if (col == 0) out[g] = t + lin_b[0];
    }
}

// ---------------- Launch ----------------

extern "C" void kernel_launch(void* const* d_in, const int* in_sizes, int n_in,
                              void* d_out, int out_size, void* d_ws, size_t ws_size,
                              hipStream_t stream) {
    const float* x     = (const float*)d_in[0];
    const int*   ei    = (const int*)d_in[1];
    const int*   batch = (const int*)d_in[2];
    const float* W0    = (const float*)d_in[3];
    const float* b0    = (const float*)d_in[4];
    const float* W1    = (const float*)d_in[5];
    const float* b1    = (const float*)d_in[6];
    const float* W2    = (const float*)d_in[7];
    const float* b2    = (const float*)d_in[8];
    const float* lin_w = (const float*)d_in[9];
    const float* lin_b = (const float*)d_in[10];

    const int N_ = in_sizes[2];
    const int E_ = in_sizes[1] / 2;
    const int G_ = out_size;
    const int* esrc = ei;
    const int* edst = ei + E_;

    // workspace layout (bytes from d_ws)
    char* p = reinterpret_cast<char*>(d_ws);
    ushort* Mbf = reinterpret_cast<ushort*>(p);        p += (size_t)N_ * F_DIM * sizeof(ushort);
    float*  Hbuf = reinterpret_cast<float*>(p);        p += (size_t)N_ * F_DIM * sizeof(float);
    float*  dinvp = reinterpret_cast<float*>(p);       p += (size_t)N_ * sizeof(float);
    int*    deg = reinterpret_cast<int*>(p);           p += (size_t)N_ * sizeof(int);
    int*    row_ptr = reinterpret_cast<int*>(p);       p += (size_t)(N_ + 4) * sizeof(int);
    int*    rfill = reinterpret_cast<int*>(p);         p += (size_t)N_ * sizeof(int);
    int*    col_src = reinterpret_cast<int*>(p);       p += (size_t)E_ * sizeof(int);
    ushort* Wth = reinterpret_cast<ushort*>(p);        p += (size_t)3 * F_DIM * F_DIM * sizeof(ushort);
    ushort* Wtl = reinterpret_cast<ushort*>(p);        p += (size_t)3 * F_DIM * F_DIM * sizeof(ushort);
    const int NB = (N_ + 255) / 256;
    int*    bsum = reinterpret_cast<int*>(p);          p += (size_t)NB * sizeof(int);
    int*    bsx = reinterpret_cast<int*>(p);
    float*  partial = reinterpret_cast<float*>(d_ws);  // alias Mbf region (dead during pooling)

    hipMemsetAsync(deg, 0, (size_t)N_ * sizeof(int), stream);

    int eb = (E_ + 255) / 256;
    wprep_kernel<<<48, 256, 0, stream>>>(W0, W1, W2, Wth, Wtl);
    count_kernel<<<eb, 256, 0, stream>>>(edst, deg, E_);
    scan_blocksums_kernel<<<NB, 256, 0, stream>>>(deg, bsum, N_);
    scan_bs_kernel<<<1, 256, 0, stream>>>(bsum, bsx, NB);
    scan_final_kernel<<<NB, 256, 0, stream>>>(deg, bsx, row_ptr, rfill, dinvp, N_, E_);
    fill_kernel<<<eb, 256, 0, stream>>>(esrc, edst, rfill, col_src, E_);

    const int gemm_grid = ((N_ + 63) / 64) * 2;
    const int gat_grid  = (N_ + 3) / 4;

    const float* cur_in = x;
    const float* bias[3] = {b0, b1, b2};
    for (int l = 0; l < 3; ++l) {
        gemm_scale_kernel<<<gemm_grid, 256, 0, stream>>>(
            cur_in, Wth + (size_t)l * F_DIM * F_DIM, Wtl + (size_t)l * F_DIM * F_DIM,
            dinvp, Mbf, N_);
        gather_kernel<<<gat_grid, 256, 0, stream>>>(
            Mbf, row_ptr, col_src, dinvp, bias[l], Hbuf, N_);
        cur_in = Hbuf;
    }

    pool_part_kernel<<<G_ * POOL_SEG, 128, 0, stream>>>(Hbuf, batch, partial, N_);
    pool_final_kernel<<<G_, 128, 0, stream>>>(partial, batch, lin_w, lin_b, (float*)d_out, N_);
}

// Round 8
// 213.885 us; speedup vs baseline: 1.3279x; 1.0667x over previous
//
#include <hip/hip_runtime.h>
#include <hip/hip_bf16.h>

#define F_DIM 128
#define POOL_SEG 16

typedef __attribute__((ext_vector_type(8))) short short8v;   // 8 bf16
typedef __attribute__((ext_vector_type(4))) float float4v;   // MFMA acc

// ---------------- helpers ----------------

__device__ __forceinline__ ushort f2bf(float f) {  // RNE f32 -> bf16
    uint u = __float_as_uint(f);
    u += 0x7fffu + ((u >> 16) & 1u);
    return (ushort)(u >> 16);
}
__device__ __forceinline__ float bf2f(ushort h) {
    return __uint_as_float(((uint)h) << 16);
}
__device__ __forceinline__ void bf2x(uint u, float& a, float& b) {
    a = __uint_as_float((u & 0x0000ffffu) << 16);
    b = __uint_as_float(u & 0xffff0000u);
}

// ---------------- CSR build ----------------

__global__ void count_kernel(const int* __restrict__ dst, int* __restrict__ deg, int E_) {
    int i = blockIdx.x * blockDim.x + threadIdx.x;
    if (i < E_) atomicAdd(&deg[dst[i]], 1);
}

__global__ void scan_blocksums_kernel(const int* __restrict__ deg, int* __restrict__ bsum, int N_) {
    __shared__ int s[256];
    int i = blockIdx.x * 256 + threadIdx.x;
    s[threadIdx.x] = (i < N_) ? deg[i] : 0;
    __syncthreads();
    for (int off = 128; off; off >>= 1) {
        if (threadIdx.x < off) s[threadIdx.x] += s[threadIdx.x + off];
        __syncthreads();
    }
    if (threadIdx.x == 0) bsum[blockIdx.x] = s[0];
}

__global__ void scan_bs_kernel(const int* __restrict__ bsum, int* __restrict__ bsx, int NB) {
    __shared__ int s[256];
    int t = threadIdx.x;
    int orig = (t < NB) ? bsum[t] : 0;
    s[t] = orig;
    __syncthreads();
    for (int off = 1; off < 256; off <<= 1) {
        int v = (t >= off) ? s[t - off] : 0;
        __syncthreads();
        s[t] += v;
        __syncthreads();
    }
    if (t < NB) bsx[t] = s[t] - orig;   // exclusive
}

__global__ void scan_final_kernel(const int* __restrict__ deg, const int* __restrict__ bsx,
                                  int* __restrict__ row_ptr, int* __restrict__ rfill,
                                  float* __restrict__ dinv, int N_, int E_) {
    __shared__ int s[256];
    int t = threadIdx.x;
    int i = blockIdx.x * 256 + t;
    int orig = (i < N_) ? deg[i] : 0;
    s[t] = orig;
    __syncthreads();
    for (int off = 1; off < 256; off <<= 1) {
        int v = (t >= off) ? s[t - off] : 0;
        __syncthreads();
        s[t] += v;
        __syncthreads();
    }
    int excl = s[t] - orig + bsx[blockIdx.x];
    if (i < N_) {
        row_ptr[i] = excl;
        rfill[i] = excl;
        dinv[i] = 1.0f / sqrtf((float)(orig + 1));   // +1 self-loop
    }
    if (i == N_ - 1) row_ptr[N_] = E_;
}

__global__ void fill_kernel(const int* __restrict__ src, const int* __restrict__ dst,
                            int* __restrict__ cur, int* __restrict__ col_src, int E_) {
    int i = blockIdx.x * blockDim.x + threadIdx.x;
    if (i < E_) {
        int p = atomicAdd(&cur[dst[i]], 1);
        col_src[p] = src[i];
    }
}

// ---------------- prep: W^T hi/lo split (blocks 0..47) + zero deg (blocks 48+) ----------------

__global__ __launch_bounds__(256) void prep_kernel(
    const float* __restrict__ W0, const float* __restrict__ W1, const float* __restrict__ W2,
    ushort* __restrict__ Wth, ushort* __restrict__ Wtl, int* __restrict__ deg, int N_)
{
    if (blockIdx.x >= 48) {
        int i = (blockIdx.x - 48) * 256 + threadIdx.x;
        if (i < N_) deg[i] = 0;
        return;
    }
    int layer = blockIdx.x >> 4;
    int chunkc = blockIdx.x & 15;
    const float* W = (layer == 0) ? W0 : (layer == 1) ? W1 : W2;
    int t = threadIdx.x;
    int c  = chunkc * 8 + (t >> 5);      // column of W
    int k0 = (t & 31) * 4;               // 4 consecutive k
    ushort4 hi, lo;
    float v0 = W[(size_t)(k0 + 0) * F_DIM + c];
    float v1 = W[(size_t)(k0 + 1) * F_DIM + c];
    float v2 = W[(size_t)(k0 + 2) * F_DIM + c];
    float v3 = W[(size_t)(k0 + 3) * F_DIM + c];
    hi.x = f2bf(v0); lo.x = f2bf(v0 - bf2f(hi.x));
    hi.y = f2bf(v1); lo.y = f2bf(v1 - bf2f(hi.y));
    hi.z = f2bf(v2); lo.z = f2bf(v2 - bf2f(hi.z));
    hi.w = f2bf(v3); lo.w = f2bf(v3 - bf2f(hi.w));
    size_t o = (size_t)layer * F_DIM * F_DIM + (size_t)c * F_DIM + k0;
    *reinterpret_cast<ushort4*>(&Wth[o]) = hi;
    *reinterpret_cast<ushort4*>(&Wtl[o]) = lo;
}

// ---------------- MFMA GEMM: Mbf[r][c] = bf16( dinv[r] * sum_k in[r][k] * W[k][c] ) ----------------
// bf16 hi/lo split, 3-term (AhBh + AlBh + AhBl) -> ~f32 accuracy.

__global__ __launch_bounds__(256) void gemm_scale_kernel(
    const float* __restrict__ in, const ushort* __restrict__ Wth, const ushort* __restrict__ Wtl,
    const float* __restrict__ dinv, ushort* __restrict__ outbf, int N_)
{
    __shared__ ushort Ah[64 * F_DIM];   // 16 KB each, XOR-swizzled k within row
    __shared__ ushort Al[64 * F_DIM];
    __shared__ ushort Bh[64 * F_DIM];   // [c][k]
    __shared__ ushort Bl[64 * F_DIM];

    const int tid = threadIdx.x;
    const int brow = (blockIdx.x >> 1) * 64;
    const int bcol = (blockIdx.x & 1) * 64;

    #pragma unroll
    for (int i = 0; i < 4; ++i) {
        int chunk = tid + i * 256;
        int r  = chunk >> 4;
        int k0 = (chunk & 15) * 8;
        int row = brow + r;
        float f[8];
        if (row < N_) {
            float4 g0 = *reinterpret_cast<const float4*>(&in[(size_t)row * F_DIM + k0]);
            float4 g1 = *reinterpret_cast<const float4*>(&in[(size_t)row * F_DIM + k0 + 4]);
            f[0] = g0.x; f[1] = g0.y; f[2] = g0.z; f[3] = g0.w;
            f[4] = g1.x; f[5] = g1.y; f[6] = g1.z; f[7] = g1.w;
        } else {
            #pragma unroll
            for (int j = 0; j < 8; ++j) f[j] = 0.f;
        }
        ushort hi[8], lo[8];
        #pragma unroll
        for (int j = 0; j < 8; ++j) {
            hi[j] = f2bf(f[j]);
            lo[j] = f2bf(f[j] - bf2f(hi[j]));
        }
        int idx = r * F_DIM + (k0 ^ ((r & 7) << 3));
        *reinterpret_cast<short8v*>(&Ah[idx]) = *reinterpret_cast<short8v*>(hi);
        *reinterpret_cast<short8v*>(&Al[idx]) = *reinterpret_cast<short8v*>(lo);
    }
    #pragma unroll
    for (int i = 0; i < 4; ++i) {
        int chunk = tid + i * 256;
        int c  = chunk >> 4;
        int k0 = (chunk & 15) * 8;
        size_t go = (size_t)(bcol + c) * F_DIM + k0;
        int idx = c * F_DIM + (k0 ^ ((c & 7) << 3));
        *reinterpret_cast<short8v*>(&Bh[idx]) = *reinterpret_cast<const short8v*>(&Wth[go]);
        *reinterpret_cast<short8v*>(&Bl[idx]) = *reinterpret_cast<const short8v*>(&Wtl[go]);
    }
    __syncthreads();

    const int l = tid & 63;
    const int wave = tid >> 6;
    const int m0 = wave * 16;
    const int row_a = m0 + (l & 15);
    const int kgrp = (l >> 4) * 8;
    const int aswz = (row_a & 7) << 3;

    float4v acc[4] = {{0.f,0.f,0.f,0.f},{0.f,0.f,0.f,0.f},{0.f,0.f,0.f,0.f},{0.f,0.f,0.f,0.f}};

    #pragma unroll
    for (int kk = 0; kk < 4; ++kk) {
        int kbase = kk * 32 + kgrp;
        short8v a_h = *reinterpret_cast<short8v*>(&Ah[row_a * F_DIM + (kbase ^ aswz)]);
        short8v a_l = *reinterpret_cast<short8v*>(&Al[row_a * F_DIM + (kbase ^ aswz)]);
        #pragma unroll
        for (int n = 0; n < 4; ++n) {
            int col_b = n * 16 + (l & 15);
            int bidx = col_b * F_DIM + (kbase ^ ((col_b & 7) << 3));
            short8v b_h = *reinterpret_cast<short8v*>(&Bh[bidx]);
            short8v b_l = *reinterpret_cast<short8v*>(&Bl[bidx]);
            acc[n] = __builtin_amdgcn_mfma_f32_16x16x32_bf16(a_h, b_h, acc[n], 0, 0, 0);
            acc[n] = __builtin_amdgcn_mfma_f32_16x16x32_bf16(a_l, b_h, acc[n], 0, 0, 0);
            acc[n] = __builtin_amdgcn_mfma_f32_16x16x32_bf16(a_h, b_l, acc[n], 0, 0, 0);
        }
    }

    #pragma unroll
    for (int i = 0; i < 4; ++i) {
        int rloc = m0 + (l >> 4) * 4 + i;
        int row = brow + rloc;
        if (row < N_) {
            float s = dinv[row];
            #pragma unroll
            for (int n = 0; n < 4; ++n) {
                ushort o = f2bf(s * acc[n][i]);
                outbf[(size_t)row * F_DIM + bcol + n * 16 + (l & 15)] = o;
            }
        }
    }
}

// ---------------- Gather-aggregate + bias + relu (bf16, burst uint4 loads) ----------------
// One wave per node. Virtual list = [self] + in-edges (total = deg+1).
// Step 1: coalesced index load (64 positions into lane regs).
// Step 2: shfl-broadcast + burst of uint4 row loads (4 positions per load).
// Unmasked groups cover only (nidx>>4) complete 16-position groups; tail is ONE
// group of 4 clamped+masked loads issued together (full MLP, valid addresses).

__global__ __launch_bounds__(256) void gather_kernel(
    const ushort* __restrict__ Mbf, const int* __restrict__ row_ptr,
    const int* __restrict__ col_src, const float* __restrict__ dinv,
    const float* __restrict__ bias, float* __restrict__ Hout, int N_)
{
    int v = blockIdx.x * 4 + (threadIdx.x >> 6);
    if (v >= N_) return;
    const int lane = threadIdx.x & 63;
    const int fq  = lane & 15;      // uint4 index within row (16 x 16B = 256B)
    const int sub = lane >> 4;      // load slot 0..3
    const uint4* M4 = reinterpret_cast<const uint4*>(Mbf);   // row stride 16

    float acc[8];
    #pragma unroll
    for (int j = 0; j < 8; ++j) acc[j] = 0.f;

    int lo = row_ptr[v];
    int total = row_ptr[v + 1] - lo + 1;    // self + in-edges

    for (int base = 0; base < total; base += 64) {
        int nidx = total - base; if (nidx > 64) nidx = 64;
        int p = base + lane;
        int idx = v;                         // position 0 of chunk 0 = self loop
        if (p > 0 && p < total) idx = col_src[lo + p - 1];

        int nslots = (nidx + 3) >> 2;        // slots of 4 positions
        int jfull  = (nidx >> 4) * 4;        // slots covered by COMPLETE 16-pos groups
        int j = 0;
        for (; j < jfull; j += 4) {
            int q0 = j * 4 + sub;            // positions q0, q0+4, q0+8, q0+12 all < nidx
            int s0 = __shfl(idx, q0);
            int s1 = __shfl(idx, q0 + 4);
            int s2 = __shfl(idx, q0 + 8);
            int s3 = __shfl(idx, q0 + 12);
            uint4 u0 = M4[(size_t)s0 * 16 + fq];
            uint4 u1 = M4[(size_t)s1 * 16 + fq];
            uint4 u2 = M4[(size_t)s2 * 16 + fq];
            uint4 u3 = M4[(size_t)s3 * 16 + fq];
            float a, b;
            bf2x(u0.x, a, b); acc[0] += a; acc[1] += b;
            bf2x(u0.y, a, b); acc[2] += a; acc[3] += b;
            bf2x(u0.z, a, b); acc[4] += a; acc[5] += b;
            bf2x(u0.w, a, b); acc[6] += a; acc[7] += b;
            bf2x(u1.x, a, b); acc[0] += a; acc[1] += b;
            bf2x(u1.y, a, b); acc[2] += a; acc[3] += b;
            bf2x(u1.z, a, b); acc[4] += a; acc[5] += b;
            bf2x(u1.w, a, b); acc[6] += a; acc[7] += b;
            bf2x(u2.x, a, b); acc[0] += a; acc[1] += b;
            bf2x(u2.y, a, b); acc[2] += a; acc[3] += b;
            bf2x(u2.z, a, b); acc[4] += a; acc[5] += b;
            bf2x(u2.w, a, b); acc[6] += a; acc[7] += b;
            bf2x(u3.x, a, b); acc[0] += a; acc[1] += b;
            bf2x(u3.y, a, b); acc[2] += a; acc[3] += b;
            bf2x(u3.z, a, b); acc[4] += a; acc[5] += b;
            bf2x(u3.w, a, b); acc[6] += a; acc[7] += b;
        }
        if (j < nslots) {                    // tail: 1..4 valid slots
            int q0 = j * 4 + sub;
            int q1 = q0 + 4, q2 = q0 + 8, q3 = q0 + 12;
            int c0 = min(q0, nidx - 1), c1 = min(q1, nidx - 1);
            int c2 = min(q2, nidx - 1), c3 = min(q3, nidx - 1);
            int s0 = __shfl(idx, c0);
            int s1 = __shfl(idx, c1);
            int s2 = __shfl(idx, c2);
            int s3 = __shfl(idx, c3);
            float m0 = (q0 < nidx) ? 1.f : 0.f;
            float m1 = (q1 < nidx) ? 1.f : 0.f;
            float m2 = (q2 < nidx) ? 1.f : 0.f;
            float m3 = (q3 < nidx) ? 1.f : 0.f;
            uint4 u0 = M4[(size_t)s0 * 16 + fq];
            uint4 u1 = M4[(size_t)s1 * 16 + fq];
            uint4 u2 = M4[(size_t)s2 * 16 + fq];
            uint4 u3 = M4[(size_t)s3 * 16 + fq];
            float a, b;
            bf2x(u0.x, a, b); acc[0] = fmaf(a, m0, acc[0]); acc[1] = fmaf(b, m0, acc[1]);
            bf2x(u0.y, a, b); acc[2] = fmaf(a, m0, acc[2]); acc[3] = fmaf(b, m0, acc[3]);
            bf2x(u0.z, a, b); acc[4] = fmaf(a, m0, acc[4]); acc[5] = fmaf(b, m0, acc[5]);
            bf2x(u0.w, a, b); acc[6] = fmaf(a, m0, acc[6]); acc[7] = fmaf(b, m0, acc[7]);
            bf2x(u1.x, a, b); acc[0] = fmaf(a, m1, acc[0]); acc[1] = fmaf(b, m1, acc[1]);
            bf2x(u1.y, a, b); acc[2] = fmaf(a, m1, acc[2]); acc[3] = fmaf(b, m1, acc[3]);
            bf2x(u1.z, a, b); acc[4] = fmaf(a, m1, acc[4]); acc[5] = fmaf(b, m1, acc[5]);
            bf2x(u1.w, a, b); acc[6] = fmaf(a, m1, acc[6]); acc[7] = fmaf(b, m1, acc[7]);
            bf2x(u2.x, a, b); acc[0] = fmaf(a, m2, acc[0]); acc[1] = fmaf(b, m2, acc[1]);
            bf2x(u2.y, a, b); acc[2] = fmaf(a, m2, acc[2]); acc[3] = fmaf(b, m2, acc[3]);
            bf2x(u2.z, a, b); acc[4] = fmaf(a, m2, acc[4]); acc[5] = fmaf(b, m2, acc[5]);
            bf2x(u2.w, a, b); acc[6] = fmaf(a, m2, acc[6]); acc[7] = fmaf(b, m2, acc[7]);
            bf2x(u3.x, a, b); acc[0] = fmaf(a, m3, acc[0]); acc[1] = fmaf(b, m3, acc[1]);
            bf2x(u3.y, a, b); acc[2] = fmaf(a, m3, acc[2]); acc[3] = fmaf(b, m3, acc[3]);
            bf2x(u3.z, a, b); acc[4] = fmaf(a, m3, acc[4]); acc[5] = fmaf(b, m3, acc[5]);
            bf2x(u3.w, a, b); acc[6] = fmaf(a, m3, acc[6]); acc[7] = fmaf(b, m3, acc[7]);
        }
    }

    #pragma unroll
    for (int j = 0; j < 8; ++j) {
        acc[j] += __shfl_xor(acc[j], 16);
        acc[j] += __shfl_xor(acc[j], 32);
    }

    if (sub == 0) {
        float dv = dinv[v];
        const float4* b4 = reinterpret_cast<const float4*>(bias);
        float4 bb0 = b4[fq * 2], bb1 = b4[fq * 2 + 1];
        float4 o0, o1;
        o0.x = fmaxf(dv * acc[0] + bb0.x, 0.0f);
        o0.y = fmaxf(dv * acc[1] + bb0.y, 0.0f);
        o0.z = fmaxf(dv * acc[2] + bb0.z, 0.0f);
        o0.w = fmaxf(dv * acc[3] + bb0.w, 0.0f);
        o1.x = fmaxf(dv * acc[4] + bb1.x, 0.0f);
        o1.y = fmaxf(dv * acc[5] + bb1.y, 0.0f);
        o1.z = fmaxf(dv * acc[6] + bb1.z, 0.0f);
        o1.w = fmaxf(dv * acc[7] + bb1.w, 0.0f);
        float4* H4 = reinterpret_cast<float4*>(&Hout[(size_t)v * F_DIM + fq * 8]);
        H4[0] = o0;
        H4[1] = o1;
    }
}

// ---------------- Mean-pool per graph + final linear (two-stage, deterministic) ----------------

__device__ __forceinline__ int lower_bound_i(const int* __restrict__ a, int n, int key) {
    int lo = 0, hi = n;
    while (lo < hi) {
        int mid = (lo + hi) >> 1;
        if (a[mid] < key) lo = mid + 1; else hi = mid;
    }
    return lo;
}

__global__ __launch_bounds__(128) void pool_part_kernel(
    const float* __restrict__ H, const int* __restrict__ batch,
    float* __restrict__ partial, int N_)
{
    int g = blockIdx.x / POOL_SEG;
    int s = blockIdx.x % POOL_SEG;
    int lo = lower_bound_i(batch, N_, g);
    int hi = lower_bound_i(batch, N_, g + 1);
    int len = hi - lo;
    int chunk = (len + POOL_SEG - 1) / POOL_SEG;
    int a = lo + s * chunk;
    int b = min(a + chunk, hi);
    int col = threadIdx.x;
    float acc = 0.f;
    for (int n = a; n < b; ++n) acc += H[(size_t)n * F_DIM + col];
    partial[((size_t)g * POOL_SEG + s) * F_DIM + col] = acc;
}

__global__ __launch_bounds__(128) void pool_final_kernel(
    const float* __restrict__ partial, const int* __restrict__ batch,
    const float* __restrict__ lin_w, const float* __restrict__ lin_b,
    float* __restrict__ out, int N_)
{
    int g = blockIdx.x;
    int col = threadIdx.x;
    float acc = 0.f;
    #pragma unroll
    for (int s = 0; s < POOL_SEG; ++s)
        acc += partial[((size_t)g * POOL_SEG + s) * F_DIM + col];
    int lo = lower_bound_i(batch, N_, g);
    int hi = lower_bound_i(batch, N_, g + 1);
    float pooled = acc / fmaxf((float)(hi - lo), 1.0f);
    float v = pooled * lin_w[col];
    __shared__ float sm[128];
    sm[col] = v;
    __syncthreads();
    if (col < 64) {
        float t = sm[col] + sm[col + 64];
        for (int off = 32; off; off >>= 1) t += __shfl_down(t, off);
        if (col == 0) out[g] = t + lin_b[0];
    }
}

// ---------------- Launch ----------------

extern "C" void kernel_launch(void* const* d_in, const int* in_sizes, int n_in,
                              void* d_out, int out_size, void* d_ws, size_t ws_size,
                              hipStream_t stream) {
    const float* x     = (const float*)d_in[0];
    const int*   ei    = (const int*)d_in[1];
    const int*   batch = (const int*)d_in[2];
    const float* W0    = (const float*)d_in[3];
    const float* b0    = (const float*)d_in[4];
    const float* W1    = (const float*)d_in[5];
    const float* b1    = (const float*)d_in[6];
    const float* W2    = (const float*)d_in[7];
    const float* b2    = (const float*)d_in[8];
    const float* lin_w = (const float*)d_in[9];
    const float* lin_b = (const float*)d_in[10];

    const int N_ = in_sizes[2];
    const int E_ = in_sizes[1] / 2;
    const int G_ = out_size;
    const int* esrc = ei;
    const int* edst = ei + E_;

    // workspace layout (bytes from d_ws)
    char* p = reinterpret_cast<char*>(d_ws);
    ushort* Mbf = reinterpret_cast<ushort*>(p);        p += (size_t)N_ * F_DIM * sizeof(ushort);
    float*  Hbuf = reinterpret_cast<float*>(p);        p += (size_t)N_ * F_DIM * sizeof(float);
    float*  dinvp = reinterpret_cast<float*>(p);       p += (size_t)N_ * sizeof(float);
    int*    deg = reinterpret_cast<int*>(p);           p += (size_t)N_ * sizeof(int);
    int*    row_ptr = reinterpret_cast<int*>(p);       p += (size_t)(N_ + 4) * sizeof(int);
    int*    rfill = reinterpret_cast<int*>(p);         p += (size_t)N_ * sizeof(int);
    int*    col_src = reinterpret_cast<int*>(p);       p += (size_t)E_ * sizeof(int);
    ushort* Wth = reinterpret_cast<ushort*>(p);        p += (size_t)3 * F_DIM * F_DIM * sizeof(ushort);
    ushort* Wtl = reinterpret_cast<ushort*>(p);        p += (size_t)3 * F_DIM * F_DIM * sizeof(ushort);
    const int NB = (N_ + 255) / 256;
    int*    bsum = reinterpret_cast<int*>(p);          p += (size_t)NB * sizeof(int);
    int*    bsx = reinterpret_cast<int*>(p);
    float*  partial = reinterpret_cast<float*>(d_ws);  // alias Mbf region (dead during pooling)

    int eb = (E_ + 255) / 256;
    prep_kernel<<<48 + NB, 256, 0, stream>>>(W0, W1, W2, Wth, Wtl, deg, N_);
    count_kernel<<<eb, 256, 0, stream>>>(edst, deg, E_);
    scan_blocksums_kernel<<<NB, 256, 0, stream>>>(deg, bsum, N_);
    scan_bs_kernel<<<1, 256, 0, stream>>>(bsum, bsx, NB);
    scan_final_kernel<<<NB, 256, 0, stream>>>(deg, bsx, row_ptr, rfill, dinvp, N_, E_);
    fill_kernel<<<eb, 256, 0, stream>>>(esrc, edst, rfill, col_src, E_);

    const int gemm_grid = ((N_ + 63) / 64) * 2;
    const int gat_grid  = (N_ + 3) / 4;

    const float* cur_in = x;
    const float* bias[3] = {b0, b1, b2};
    for (int l = 0; l < 3; ++l) {
        gemm_scale_kernel<<<gemm_grid, 256, 0, stream>>>(
            cur_in, Wth + (size_t)l * F_DIM * F_DIM, Wtl + (size_t)l * F_DIM * F_DIM,
            dinvp, Mbf, N_);
        gather_kernel<<<gat_grid, 256, 0, stream>>>(
            Mbf, row_ptr, col_src, dinvp, bias[l], Hbuf, N_);
        cur_in = Hbuf;
    }

    pool_part_kernel<<<G_ * POOL_SEG, 128, 0, stream>>>(Hbuf, batch, partial, N_);
    pool_final_kernel<<<G_, 128, 0, stream>>>(partial, batch, lin_w, lin_b, (float*)d_out, N_);
}